// Round 4
// baseline (73.950 us; speedup 1.0000x reference)
//
#include <hip/hip_runtime.h>

// ---------------------------------------------------------------------------
// SNN Perceptron Equalizer (LIF recurrent net), MI355X
//
//  * xt @ W_in^T  ->  <=3 precomputed partial-dot rows P[t][seg][sym][h]
//    (invalid 3rd segments zero-filled; sym index 41 padded to 0).
//  * One WAVE per batch element; lane l holds h = 4l..4l+3 (f32x4 state,
//    packed-f32 VALU). Spike masks via __ballot -> no barriers in the scan.
//  * Recurrence z@W_rec^T: lane-parallel compaction (mbcnt ranks -> LDS
//    list scatter, dummy-padded with zero-row id 256), then batched
//    ds_read_b128 + up to 12 global_load_dwordx4 issued one timestep AHEAD
//    of consumption -> no exposed per-spike L2 latency.
//  * Consume-early / issue-late: step t consumes loads issued at t-1.
//  * z_sum[b,:] = 32*b_out + sum_h cnt[b,h]*W_out[:,h]; rate = spikes/2^25.
// ---------------------------------------------------------------------------

typedef float f32x4 __attribute__((ext_vector_type(4)));
typedef int   i32x4 __attribute__((ext_vector_type(4)));

#define T_STEPS 32
#define FDIM    41
#define ODIM    16
#define BDIM    4096
#define MF      164

#define P_FLOATS  (32 * 3 * 16 * 256)
#define WT_ROWS   257                 // row 256 = zeros (dummy slot target)
#define WT_FLOATS (WT_ROWS * 256)

__device__ __forceinline__ unsigned mbcnt64(unsigned long long m) {
    unsigned lo = __builtin_amdgcn_mbcnt_lo((unsigned)m, 0u);
    return __builtin_amdgcn_mbcnt_hi((unsigned)(m >> 32), lo);
}

// ---------------------------------------------------------------------------
// K1: build P table (fp64 accum, W_in reused across all 16 symbols),
//     transpose W_rec (+ zero row 256), zero spike counter.
// ---------------------------------------------------------------------------
__global__ __launch_bounds__(256) void k_prep(const float* __restrict__ emb,
                                              const float* __restrict__ W_in,
                                              const float* __restrict__ W_rec,
                                              float* __restrict__ P,
                                              float* __restrict__ WT,
                                              int* __restrict__ counter)
{
    const int bid = blockIdx.x;
    const int tid = threadIdx.x;

    if (bid < 96) {
        const int t  = bid / 3;
        const int si = bid % 3;
        const int k0   = t * MF;
        const int f    = (k0 >> 7) + si;
        const int base = f << 7;
        const int c0   = max(k0, base) - base;
        const int c1   = min(k0 + MF, base + 128) - base;
        const int len  = c1 - c0;

        if (len <= 0) {
            #pragma unroll
            for (int s = 0; s < 16; ++s)
                P[((t * 3 + si) * 16 + s) * 256 + tid] = 0.0f;
            return;
        }

        __shared__ float emb_lds[16][128];
        for (int idx = tid; idx < 16 * 128; idx += 256) {
            const int s = idx >> 7, u = idx & 127;
            if (u < len) emb_lds[s][u] = emb[(s << 7) + c0 + u];
        }
        __syncthreads();

        const int j0 = base + c0 - k0;
        double acc[16];
        #pragma unroll
        for (int s = 0; s < 16; ++s) acc[s] = 0.0;
        for (int u = 0; u < len; ++u) {
            const double w = (double)W_in[tid * MF + j0 + u];
            #pragma unroll
            for (int s = 0; s < 16; ++s)
                acc[s] += w * (double)emb_lds[s][u];
        }
        #pragma unroll
        for (int s = 0; s < 16; ++s)
            P[((t * 3 + si) * 16 + s) * 256 + tid] = (float)acc[s];
    } else {
        const int h = bid - 96;                 // 0..256
        if (h < 256) {
            WT[h * 256 + tid] = W_rec[tid * 256 + h];
        } else {
            WT[256 * 256 + tid] = 0.0f;         // dummy zero row
            if (tid == 0) *counter = 0;
        }
    }
}

// ---------------------------------------------------------------------------
// K2: main LIF scan. grid = BDIM/4 blocks, 4 independent waves/block.
// ---------------------------------------------------------------------------
__global__ __launch_bounds__(256) void k_main(const int* __restrict__ x,
                                              const float* __restrict__ P,
                                              const float* __restrict__ WT,
                                              const float* __restrict__ W_out,
                                              const float* __restrict__ b_out,
                                              float* __restrict__ out,
                                              int* __restrict__ counter)
{
#pragma clang fp contract(off)
    __shared__ int   list_lds[4][256];
    __shared__ int   xs_lds[4][48];
    __shared__ float cnt_lds[4][256];
    __shared__ int   red[4];

    const int tid  = threadIdx.x;
    const int lane = tid & 63;
    const int wv   = __builtin_amdgcn_readfirstlane(tid >> 6);
    const int b    = blockIdx.x * 4 + wv;

    const f32x4* __restrict__ P4  = (const f32x4*)P;
    const f32x4* __restrict__ WT4 = (const f32x4*)WT;
    int* L   = list_lds[wv];
    int* xsL = xs_lds[wv];

    // stage this wave's symbols (pad to 0 so f0+2==41 is harmless: P seg2
    // rows at those t are zero-filled anyway)
    if (lane < 48) xsL[lane] = (lane < FDIM) ? x[b * FDIM + lane] : 0;

    f32x4 vm  = {0.f, 0.f, 0.f, 0.f};
    f32x4 cur = {0.f, 0.f, 0.f, 0.f};
    int n0 = 0, n1 = 0, n2 = 0, n3 = 0;

    f32x4 wA[12], wB[12];
    f32x4 pA0, pA1, pA2, pB0, pB1, pB2;
    f32x4 rextA = {0.f, 0.f, 0.f, 0.f}, rextB;
    int   cntA = 0, cntB;
    #pragma unroll
    for (int k = 0; k < 12; ++k) { wA[k] = rextA; wB[k] = rextA; }
    pB0 = pB1 = pB2 = rextA; rextB = rextA; cntB = 0;

    // prefetch feedforward rows for t = 0
    {
        const int s0 = xsL[0], s1 = xsL[1], s2 = xsL[2];
        pA0 = P4[(0 * 16 + s0) * 64 + lane];
        pA1 = P4[(1 * 16 + s1) * 64 + lane];
        pA2 = P4[(2 * 16 + s2) * 64 + lane];
    }

    // One LIF step: consumes loads issued last step (C set), issues for the
    // next (N set). TT1 = timestep whose P rows to prefetch; ISSP = valid.
    #define STEP(TT1, ISSP, C, N)                                             \
    {                                                                         \
        /* --- 1. decay + spike decision (critical chain) --- */              \
        const f32x4 df   = cur - vm;                                          \
        const f32x4 vdec = vm + 0.1f * df;                                    \
        const f32x4 idec = cur * 0.8f;                                        \
        const bool z0 = vdec.x > 1.0f, z1 = vdec.y > 1.0f,                    \
                   z2 = vdec.z > 1.0f, z3 = vdec.w > 1.0f;                    \
        const unsigned long long m0 = __ballot(z0), m1 = __ballot(z1),        \
                                 m2 = __ballot(z2), m3 = __ballot(z3);        \
        vm.x = z0 ? 0.0f : vdec.x;  vm.y = z1 ? 0.0f : vdec.y;                \
        vm.z = z2 ? 0.0f : vdec.z;  vm.w = z3 ? 0.0f : vdec.w;                \
        n0 += z0; n1 += z1; n2 += z2; n3 += z3;                               \
        /* --- 2. consume: ff + rec from loads issued LAST step --- */        \
        const f32x4 ff = (p##C##0 + p##C##1) + p##C##2;                       \
        f32x4 rec = rext##C;                                                  \
        if (cnt##C > 0) { rec += w##C[0];  rec += w##C[1];                    \
                          rec += w##C[2];  rec += w##C[3]; }                  \
        if (cnt##C > 4) { rec += w##C[4];  rec += w##C[5];                    \
                          rec += w##C[6];  rec += w##C[7]; }                  \
        if (cnt##C > 8) { rec += w##C[8];  rec += w##C[9];                    \
                          rec += w##C[10]; rec += w##C[11]; }                 \
        cur = (idec + ff) + rec;                                              \
        /* --- 3. issue next step's P rows --- */                             \
        if (ISSP) {                                                           \
            const int f0_ = ((TT1) * MF) >> 7;                                \
            const int s0_ = xsL[f0_], s1_ = xsL[f0_ + 1], s2_ = xsL[f0_ + 2]; \
            p##N##0 = P4[(((TT1) * 3 + 0) * 16 + s0_) * 64 + lane];           \
            p##N##1 = P4[(((TT1) * 3 + 1) * 16 + s1_) * 64 + lane];           \
            p##N##2 = P4[(((TT1) * 3 + 2) * 16 + s2_) * 64 + lane];           \
        }                                                                     \
        /* --- 4. compact spikes, issue next step's WT rows --- */            \
        const int c0_ = __popcll(m0), c1_ = __popcll(m1),                     \
                  c2_ = __popcll(m2), c3_ = __popcll(m3);                     \
        const int o1_ = c0_, o2_ = o1_ + c1_, o3_ = o2_ + c2_;                \
        cnt##N = o3_ + c3_;                                                   \
        const unsigned r0_ = mbcnt64(m0), r1_ = mbcnt64(m1),                  \
                       r2_ = mbcnt64(m2), r3_ = mbcnt64(m3);                  \
        if (lane < 12) L[lane] = 256;      /* dummy-pad (zero row) */         \
        if (z0) L[      r0_] = 4 * lane + 0;                                  \
        if (z1) L[o1_ + r1_] = 4 * lane + 1;                                  \
        if (z2) L[o2_ + r2_] = 4 * lane + 2;                                  \
        if (z3) L[o3_ + r3_] = 4 * lane + 3;                                  \
        rext##N = (f32x4){0.f, 0.f, 0.f, 0.f};                                \
        if (cnt##N > 0) {                                                     \
            const i32x4 u = *(const i32x4*)&L[0];                             \
            w##N[0] = WT4[u.x * 64 + lane]; w##N[1] = WT4[u.y * 64 + lane];   \
            w##N[2] = WT4[u.z * 64 + lane]; w##N[3] = WT4[u.w * 64 + lane];   \
        }                                                                     \
        if (cnt##N > 4) {                                                     \
            const i32x4 u = *(const i32x4*)&L[4];                             \
            w##N[4] = WT4[u.x * 64 + lane]; w##N[5] = WT4[u.y * 64 + lane];   \
            w##N[6] = WT4[u.z * 64 + lane]; w##N[7] = WT4[u.w * 64 + lane];   \
        }                                                                     \
        if (cnt##N > 8) {                                                     \
            const i32x4 u = *(const i32x4*)&L[8];                             \
            w##N[8]  = WT4[u.x * 64 + lane]; w##N[9]  = WT4[u.y * 64 + lane]; \
            w##N[10] = WT4[u.z * 64 + lane]; w##N[11] = WT4[u.w * 64 + lane]; \
        }                                                                     \
        if (cnt##N > 12) {               /* rare overflow: batched by 4 */    \
            int k_ = 12;                                                      \
            for (; k_ + 3 < cnt##N; k_ += 4) {                                \
                const i32x4 u = *(const i32x4*)&L[k_];                        \
                const f32x4 a0 = WT4[u.x * 64 + lane];                        \
                const f32x4 a1 = WT4[u.y * 64 + lane];                        \
                const f32x4 a2 = WT4[u.z * 64 + lane];                        \
                const f32x4 a3 = WT4[u.w * 64 + lane];                        \
                rext##N += ((a0 + a1) + (a2 + a3));                           \
            }                                                                 \
            for (; k_ < cnt##N; ++k_)                                         \
                rext##N += WT4[L[k_] * 64 + lane];                            \
        }                                                                     \
    }

    for (int tt = 0; tt < T_STEPS; tt += 2) {
        STEP(tt + 1, 1, A, B);
        STEP(tt + 2, (tt + 2 < T_STEPS), B, A);
    }
    #undef STEP

    // --- publish per-h spike counts & block spike total ---
    cnt_lds[wv][4 * lane + 0] = (float)n0;
    cnt_lds[wv][4 * lane + 1] = (float)n1;
    cnt_lds[wv][4 * lane + 2] = (float)n2;
    cnt_lds[wv][4 * lane + 3] = (float)n3;

    int myspk = n0 + n1 + n2 + n3;
    #pragma unroll
    for (int off = 32; off > 0; off >>= 1)
        myspk += __shfl_down(myspk, off, 64);
    if (lane == 0) red[wv] = myspk;

    __syncthreads();
    if (tid == 0) atomicAdd(counter, red[0] + red[1] + red[2] + red[3]);

    // --- epilogue: z_sum[b,o] = 32*b_out[o] + sum_h cnt[h]*W_out[o,h] ---
    {
        const int o = lane & 15;
        const int q = lane >> 4;
        const float* __restrict__ wo = W_out + o * 256 + q * 64;
        const float* __restrict__ cl = cnt_lds[wv] + q * 64;
        float acc = 0.0f;
        #pragma unroll 8
        for (int h = 0; h < 64; ++h)
            acc += cl[h] * wo[h];
        acc += __shfl_down(acc, 16, 64);
        acc += __shfl_down(acc, 32, 64);
        if (q == 0)
            out[b * ODIM + o] = 32.0f * b_out[o] + acc;
    }
}

// ---------------------------------------------------------------------------
// K3: spikerate = count / 2^25 (exact in fp32 since count < 2^24)
// ---------------------------------------------------------------------------
__global__ void k_fin(const int* __restrict__ counter, float* __restrict__ out)
{
    out[BDIM * ODIM] = (float)(*counter) * (1.0f / 33554432.0f);
}

// ---------------------------------------------------------------------------
extern "C" void kernel_launch(void* const* d_in, const int* in_sizes, int n_in,
                              void* d_out, int out_size, void* d_ws, size_t ws_size,
                              hipStream_t stream)
{
    const int*   x     = (const int*)  d_in[0];
    const float* emb   = (const float*)d_in[1];
    const float* W_in  = (const float*)d_in[2];
    const float* W_rec = (const float*)d_in[3];
    const float* W_out = (const float*)d_in[4];
    const float* b_out = (const float*)d_in[5];
    float* out = (float*)d_out;

    float* P       = (float*)d_ws;
    float* WT      = P + P_FLOATS;
    int*   counter = (int*)(WT + WT_FLOATS);

    k_prep<<<96 + 257, 256, 0, stream>>>(emb, W_in, W_rec, P, WT, counter);
    k_main<<<BDIM / 4, 256, 0, stream>>>(x, P, WT, W_out, b_out, out, counter);
    k_fin<<<1, 1, 0, stream>>>(counter, out);
}

// Round 5
// 47.735 us; speedup vs baseline: 1.5492x; 1.5492x over previous
//
#include <hip/hip_runtime.h>

// ---------------------------------------------------------------------------
// SNN Perceptron Equalizer (LIF recurrent net), MI355X
//
//  * xt @ W_in^T  ->  <=3 precomputed partial-dot rows P[t][seg][sym][h];
//    only 8/32 timesteps have a 3rd segment (compile-time HAS3), rest skip it.
//  * One WAVE per batch element; lane l holds h = 4l..4l+3 (f32x4 state).
//    Spike masks via __ballot live in SGPRs -> spike ids peeled with pure
//    SALU (s_ff1 chains), NO LDS in the 32-step scan.
//  * Up to 4 W_rec^T rows prefetched into NAMED registers one step ahead
//    (small footprint so regalloc keeps the pipeline); dummy zero-row 256
//    pads; >4 spikes (rare) handled synchronously.
//  * z_sum[b,:] = 32*b_out + sum_h cnt[b,h]*W_out[:,h]; rate = spikes/2^25.
// ---------------------------------------------------------------------------

typedef float f32x4 __attribute__((ext_vector_type(4)));

#define T_STEPS 32
#define FDIM    41
#define ODIM    16
#define BDIM    4096
#define MF      164

#define P_FLOATS  (32 * 3 * 16 * 256)
#define WT_ROWS   257                 // row 256 = zeros (dummy slot target)
#define WT_FLOATS (WT_ROWS * 256)

// does timestep T span 3 embedding rows?  ((164T)&127) > 92
#define HAS3(T) ((((T) * MF) & 127) > 92)

// ---------------------------------------------------------------------------
// K1: build P table (fp64 accum; 4-symbol groups for 4x more parallelism),
//     transpose W_rec (+ zero row 256), zero spike counter.
// blocks 0..383: (t,seg,symgroup) P-builders; 384..640: transpose + zero row.
// ---------------------------------------------------------------------------
__global__ __launch_bounds__(256) void k_prep(const float* __restrict__ emb,
                                              const float* __restrict__ W_in,
                                              const float* __restrict__ W_rec,
                                              float* __restrict__ P,
                                              float* __restrict__ WT,
                                              int* __restrict__ counter)
{
    const int bid = blockIdx.x;
    const int tid = threadIdx.x;

    if (bid < 384) {
        const int g  = bid & 3;          // symbol group: symbols 4g..4g+3
        const int ts = bid >> 2;
        const int t  = ts / 3;
        const int si = ts % 3;
        const int k0   = t * MF;
        const int f    = (k0 >> 7) + si;
        const int base = f << 7;
        const int c0   = max(k0, base) - base;
        const int c1   = min(k0 + MF, base + 128) - base;
        const int len  = c1 - c0;

        if (len <= 0) {
            #pragma unroll
            for (int s = 0; s < 4; ++s)
                P[((t * 3 + si) * 16 + 4 * g + s) * 256 + tid] = 0.0f;
            return;
        }

        __shared__ float emb_lds[4][128];
        for (int idx = tid; idx < 4 * 128; idx += 256) {
            const int s = idx >> 7, u = idx & 127;
            if (u < len) emb_lds[s][u] = emb[((4 * g + s) << 7) + c0 + u];
        }
        __syncthreads();

        const int j0 = base + c0 - k0;   // window-local start column
        double a0 = 0.0, a1 = 0.0, a2 = 0.0, a3 = 0.0;
        for (int u = 0; u < len; ++u) {
            const double w = (double)W_in[tid * MF + j0 + u];
            a0 += w * (double)emb_lds[0][u];
            a1 += w * (double)emb_lds[1][u];
            a2 += w * (double)emb_lds[2][u];
            a3 += w * (double)emb_lds[3][u];
        }
        P[((t * 3 + si) * 16 + 4 * g + 0) * 256 + tid] = (float)a0;
        P[((t * 3 + si) * 16 + 4 * g + 1) * 256 + tid] = (float)a1;
        P[((t * 3 + si) * 16 + 4 * g + 2) * 256 + tid] = (float)a2;
        P[((t * 3 + si) * 16 + 4 * g + 3) * 256 + tid] = (float)a3;
    } else {
        const int h = bid - 384;                // 0..256
        if (h < 256) {
            WT[h * 256 + tid] = W_rec[tid * 256 + h];
        } else {
            WT[256 * 256 + tid] = 0.0f;         // dummy zero row
            if (tid == 0) *counter = 0;
        }
    }
}

// ---------------------------------------------------------------------------
// K2: main LIF scan. grid = BDIM/4 blocks, 4 independent waves/block.
// ---------------------------------------------------------------------------
__global__ __launch_bounds__(256) void k_main(const int* __restrict__ x,
                                              const float* __restrict__ P,
                                              const float* __restrict__ WT,
                                              const float* __restrict__ W_out,
                                              const float* __restrict__ b_out,
                                              float* __restrict__ out,
                                              int* __restrict__ counter)
{
#pragma clang fp contract(off)
    __shared__ float cnt_lds[4][256];
    __shared__ int   red[4];

    const int tid  = threadIdx.x;
    const int lane = tid & 63;
    const int wv   = __builtin_amdgcn_readfirstlane(tid >> 6);
    const int b    = blockIdx.x * 4 + wv;

    const f32x4* __restrict__ P4  = (const f32x4*)P;
    const f32x4* __restrict__ WT4 = (const f32x4*)WT;

    // symbols: one coalesced load, then readlane -> SGPRs
    const int xv = (lane < FDIM) ? x[b * FDIM + lane] : 0;
    int sym[FDIM];
    #pragma unroll
    for (int f = 0; f < FDIM; ++f)
        sym[f] = __builtin_amdgcn_readlane(xv, f);

    const f32x4 zero4 = {0.f, 0.f, 0.f, 0.f};
    f32x4 vm = zero4, cur = zero4;
    int n0 = 0, n1 = 0, n2 = 0, n3 = 0;

    f32x4 pA0 = zero4, pA1 = zero4, pA2 = zero4;
    f32x4 pB0 = zero4, pB1 = zero4, pB2 = zero4;
    f32x4 wA0 = zero4, wA1 = zero4, wA2 = zero4, wA3 = zero4;
    f32x4 wB0 = zero4, wB1 = zero4, wB2 = zero4, wB3 = zero4;
    f32x4 rextA = zero4, rextB = zero4;
    int cntA = 0, cntB = 0;

    // prefetch feedforward rows for t = 0 (t=0 has 2 segments)
    pA0 = P4[(0 * 16 + sym[0]) * 64 + lane];
    pA1 = P4[(1 * 16 + sym[1]) * 64 + lane];

    // peel one spiking unit id (uniform SALU) from masks m0..m3; 256 = dummy
    #define PEEL(dst)                                                         \
        do {                                                                  \
            if (m0)      { dst = 4 * __builtin_ctzll(m0) + 0; m0 &= m0 - 1; } \
            else if (m1) { dst = 4 * __builtin_ctzll(m1) + 1; m1 &= m1 - 1; } \
            else if (m2) { dst = 4 * __builtin_ctzll(m2) + 2; m2 &= m2 - 1; } \
            else if (m3) { dst = 4 * __builtin_ctzll(m3) + 3; m3 &= m3 - 1; } \
        } while (0)

    // One LIF step: consumes loads issued last step (C), issues next (N).
    #define STEP(TC, C, N, LAST)                                              \
    {                                                                         \
        /* 1. membrane decay + spike decision */                              \
        const f32x4 vdec = vm + 0.1f * (cur - vm);                            \
        const f32x4 idec = cur * 0.8f;                                        \
        const bool z0 = vdec.x > 1.0f, z1 = vdec.y > 1.0f,                    \
                   z2 = vdec.z > 1.0f, z3 = vdec.w > 1.0f;                    \
        unsigned long long m0 = __ballot(z0), m1 = __ballot(z1),              \
                           m2 = __ballot(z2), m3 = __ballot(z3);              \
        vm.x = z0 ? 0.0f : vdec.x;  vm.y = z1 ? 0.0f : vdec.y;                \
        vm.z = z2 ? 0.0f : vdec.z;  vm.w = z3 ? 0.0f : vdec.w;                \
        n0 += z0; n1 += z1; n2 += z2; n3 += z3;                               \
        /* 2. consume prefetched ff + rec */                                  \
        f32x4 ff = p##C##0 + p##C##1;                                         \
        if (HAS3(TC)) ff = ff + p##C##2;                                      \
        f32x4 rec = rext##C;                                                  \
        if (cnt##C > 0) { rec += w##C##0; rec += w##C##1;                     \
                          rec += w##C##2; rec += w##C##3; }                   \
        cur = (idec + ff) + rec;                                              \
        /* 3. issue next step's P rows (static addresses) */                  \
        if (!(LAST)) {                                                        \
            const int f0_ = (((TC) + 1) * MF) >> 7;                           \
            p##N##0 = P4[((((TC) + 1) * 3 + 0) * 16 + sym[f0_    ]) * 64 + lane]; \
            p##N##1 = P4[((((TC) + 1) * 3 + 1) * 16 + sym[f0_ + 1]) * 64 + lane]; \
            if (HAS3((TC) + 1))                                               \
                p##N##2 = P4[((((TC) + 1) * 3 + 2) * 16 + sym[f0_ + 2]) * 64 + lane]; \
        }                                                                     \
        /* 4. SALU peel + issue next step's WT rows */                        \
        if (!(LAST)) {                                                        \
            const int c = __popcll(m0) + __popcll(m1)                         \
                        + __popcll(m2) + __popcll(m3);                        \
            cnt##N = c;                                                       \
            rext##N = zero4;                                                  \
            if (c > 0) {                                                      \
                int u0 = 256, u1 = 256, u2 = 256, u3 = 256;                   \
                PEEL(u0); PEEL(u1); PEEL(u2); PEEL(u3);                       \
                w##N##0 = WT4[u0 * 64 + lane];                                \
                w##N##1 = WT4[u1 * 64 + lane];                                \
                w##N##2 = WT4[u2 * 64 + lane];                                \
                w##N##3 = WT4[u3 * 64 + lane];                                \
                if (c > 4) {            /* rare burst: synchronous */         \
                    while (m0) { const int l = __builtin_ctzll(m0); m0 &= m0 - 1; \
                                 rext##N += WT4[(4 * l + 0) * 64 + lane]; }   \
                    while (m1) { const int l = __builtin_ctzll(m1); m1 &= m1 - 1; \
                                 rext##N += WT4[(4 * l + 1) * 64 + lane]; }   \
                    while (m2) { const int l = __builtin_ctzll(m2); m2 &= m2 - 1; \
                                 rext##N += WT4[(4 * l + 2) * 64 + lane]; }   \
                    while (m3) { const int l = __builtin_ctzll(m3); m3 &= m3 - 1; \
                                 rext##N += WT4[(4 * l + 3) * 64 + lane]; }   \
                }                                                             \
            }                                                                 \
        }                                                                     \
    }

    STEP( 0, A, B, 0)  STEP( 1, B, A, 0)  STEP( 2, A, B, 0)  STEP( 3, B, A, 0)
    STEP( 4, A, B, 0)  STEP( 5, B, A, 0)  STEP( 6, A, B, 0)  STEP( 7, B, A, 0)
    STEP( 8, A, B, 0)  STEP( 9, B, A, 0)  STEP(10, A, B, 0)  STEP(11, B, A, 0)
    STEP(12, A, B, 0)  STEP(13, B, A, 0)  STEP(14, A, B, 0)  STEP(15, B, A, 0)
    STEP(16, A, B, 0)  STEP(17, B, A, 0)  STEP(18, A, B, 0)  STEP(19, B, A, 0)
    STEP(20, A, B, 0)  STEP(21, B, A, 0)  STEP(22, A, B, 0)  STEP(23, B, A, 0)
    STEP(24, A, B, 0)  STEP(25, B, A, 0)  STEP(26, A, B, 0)  STEP(27, B, A, 0)
    STEP(28, A, B, 0)  STEP(29, B, A, 0)  STEP(30, A, B, 0)  STEP(31, B, A, 1)

    #undef STEP
    #undef PEEL

    // --- publish per-h spike counts & block spike total ---
    cnt_lds[wv][4 * lane + 0] = (float)n0;
    cnt_lds[wv][4 * lane + 1] = (float)n1;
    cnt_lds[wv][4 * lane + 2] = (float)n2;
    cnt_lds[wv][4 * lane + 3] = (float)n3;

    int myspk = n0 + n1 + n2 + n3;
    #pragma unroll
    for (int off = 32; off > 0; off >>= 1)
        myspk += __shfl_down(myspk, off, 64);
    if (lane == 0) red[wv] = myspk;

    __syncthreads();
    if (tid == 0) atomicAdd(counter, red[0] + red[1] + red[2] + red[3]);

    // --- epilogue: z_sum[b,o] = 32*b_out[o] + sum_h cnt[h]*W_out[o,h] ---
    {
        const int o = lane & 15;
        const int q = lane >> 4;
        const float* __restrict__ wo = W_out + o * 256 + q * 64;
        const float* __restrict__ cl = cnt_lds[wv] + q * 64;
        float acc = 0.0f;
        #pragma unroll 8
        for (int h = 0; h < 64; ++h)
            acc += cl[h] * wo[h];
        acc += __shfl_down(acc, 16, 64);
        acc += __shfl_down(acc, 32, 64);
        if (q == 0)
            out[b * ODIM + o] = 32.0f * b_out[o] + acc;
    }
}

// ---------------------------------------------------------------------------
// K3: spikerate = count / 2^25 (exact in fp32 since count < 2^24)
// ---------------------------------------------------------------------------
__global__ void k_fin(const int* __restrict__ counter, float* __restrict__ out)
{
    out[BDIM * ODIM] = (float)(*counter) * (1.0f / 33554432.0f);
}

// ---------------------------------------------------------------------------
extern "C" void kernel_launch(void* const* d_in, const int* in_sizes, int n_in,
                              void* d_out, int out_size, void* d_ws, size_t ws_size,
                              hipStream_t stream)
{
    const int*   x     = (const int*)  d_in[0];
    const float* emb   = (const float*)d_in[1];
    const float* W_in  = (const float*)d_in[2];
    const float* W_rec = (const float*)d_in[3];
    const float* W_out = (const float*)d_in[4];
    const float* b_out = (const float*)d_in[5];
    float* out = (float*)d_out;

    float* P       = (float*)d_ws;
    float* WT      = P + P_FLOATS;
    int*   counter = (int*)(WT + WT_FLOATS);

    k_prep<<<384 + 257, 256, 0, stream>>>(emb, W_in, W_rec, P, WT, counter);
    k_main<<<BDIM / 4, 256, 0, stream>>>(x, P, WT, W_out, b_out, out, counter);
    k_fin<<<1, 1, 0, stream>>>(counter, out);
}